// Round 7
// baseline (134.529 us; speedup 1.0000x reference)
//
#include <hip/hip_runtime.h>

#define N_NODES 50000
#define N_EDGES 800000
#define D_FEAT  128
#define EPS     1e-12f

#define S1_BLOCK 256
#define S1_TILE  1024                                   // 4 elems/thread
#define S1_NBLK  ((N_NODES + S1_TILE - 1) / S1_TILE)    // 49

__device__ __forceinline__ unsigned int f2bf(float x) {
    unsigned int u = __float_as_uint(x);
    return (u + 0x7FFFu + ((u >> 16) & 1u)) >> 16;      // RNE
}
__device__ __forceinline__ float bf_lo(unsigned int w) {
    return __uint_as_float(w << 16);
}
__device__ __forceinline__ float bf_hi(unsigned int w) {
    return __uint_as_float(w & 0xFFFF0000u);
}

// ---------------------------------------------------------------------------
// K1: per-node inv_norm + packed bf16 copy of feat; fused per-edge dst count
// that ALSO records each edge's within-node rank (atomic return value).
// ---------------------------------------------------------------------------
__global__ void norm_kernel(const float* __restrict__ feat,
                            float* __restrict__ inv_norm,
                            unsigned int* __restrict__ feat_bf,   // 64 words/row
                            const int* __restrict__ dst,
                            int* __restrict__ counts,
                            int* __restrict__ rank) {
    const int tid = blockIdx.x * blockDim.x + threadIdx.x;
    if (tid < N_EDGES) {
        rank[tid] = atomicAdd(&counts[dst[tid]], 1);
    }
    const int lane = threadIdx.x & 63;
    const int node = blockIdx.x * (blockDim.x >> 6) + (threadIdx.x >> 6);
    if (node >= N_NODES) return;
    const float2* row = reinterpret_cast<const float2*>(feat + (size_t)node * D_FEAT);
    float2 v = row[lane];
    feat_bf[(size_t)node * 64 + lane] = (f2bf(v.y) << 16) | f2bf(v.x);
    float s = v.x * v.x + v.y * v.y;
    #pragma unroll
    for (int off = 32; off > 0; off >>= 1)
        s += __shfl_xor(s, off, 64);
    if (lane == 0) {
        inv_norm[node] = 1.0f / fmaxf(sqrtf(s), EPS);
    }
}

// ---------------------------------------------------------------------------
// Single-dispatch scan: each block computes its preceding-tiles prefix by a
// cooperative strided sum over counts[0 .. tile0), then scans its own tile.
// ---------------------------------------------------------------------------
__global__ void scan_kernel(const int* __restrict__ counts,
                            int* __restrict__ offsets) {
    __shared__ int lds[S1_BLOCK];
    const int b = blockIdx.x, t = threadIdx.x;
    const int tile0 = b * S1_TILE;

    // Phase B: before = sum(counts[0 .. tile0))
    int psum = 0;
    for (int i = t; i < tile0; i += S1_BLOCK) psum += counts[i];
    lds[t] = psum;
    __syncthreads();
    for (int off = S1_BLOCK / 2; off > 0; off >>= 1) {
        if (t < off) lds[t] += lds[t + off];
        __syncthreads();
    }
    const int before = lds[0];
    __syncthreads();

    // Phase A: own tile scan (4 elems/thread via int4)
    const int base = tile0 + t * 4;
    int v0 = 0, v1 = 0, v2 = 0, v3 = 0;
    if (base + 3 < N_NODES) {
        int4 v = *reinterpret_cast<const int4*>(counts + base);
        v0 = v.x; v1 = v.y; v2 = v.z; v3 = v.w;
    }
    const int tsum = v0 + v1 + v2 + v3;
    lds[t] = tsum;
    __syncthreads();
    for (int off = 1; off < S1_BLOCK; off <<= 1) {
        int x = (t >= off) ? lds[t - off] : 0;
        __syncthreads();
        lds[t] += x;
        __syncthreads();
    }
    const int excl = before + lds[t] - tsum;
    if (base + 3 < N_NODES) {
        *reinterpret_cast<int4*>(offsets + base) =
            make_int4(excl, excl + v0, excl + v0 + v1, excl + v0 + v1 + v2);
    }
    if (b == S1_NBLK - 1 && t == S1_BLOCK - 1)
        offsets[N_NODES] = before + lds[S1_BLOCK - 1];
}

// ---------------------------------------------------------------------------
// K4: atomic-free scatter: sorted_src[offsets[dst[e]] + rank[e]] = src[e].
// ---------------------------------------------------------------------------
__global__ void scatter_kernel(const int* __restrict__ src,
                               const int* __restrict__ dst,
                               const int* __restrict__ offsets,
                               const int* __restrict__ rank,
                               int* __restrict__ sorted_src) {
    const int e = blockIdx.x * blockDim.x + threadIdx.x;
    if (e >= N_EDGES) return;
    sorted_src[offsets[dst[e]] + rank[e]] = src[e];
}

// ---------------------------------------------------------------------------
// K5: fused per-node weight + aggregation over bf16 rows.
// One wave per node; 4 edges/iter via 16-lane groups (uint4 = 8 bf16 each).
// Software-pipelined: src ids preloaded per 64-edge chunk (register shuffles),
// next group's rows + inv_norm prefetched before computing current group.
// ---------------------------------------------------------------------------
__global__ void fused_agg(const unsigned int* __restrict__ feat_bf,
                          const float* __restrict__ inv_norm,
                          const int* __restrict__ offsets,
                          const int* __restrict__ sorted_src,
                          const float* __restrict__ beta,
                          float* __restrict__ out) {
    const int lane = threadIdx.x & 63;
    const int grp  = lane >> 4;       // 0..3  : edge slot
    const int sub  = lane & 15;       // lane within group
    const int node = blockIdx.x * (blockDim.x >> 6) + (threadIdx.x >> 6);
    if (node >= N_NODES) return;

    const int kBeg = offsets[node];
    const int kEnd = offsets[node + 1];

    const uint4* rd = reinterpret_cast<const uint4*>(feat_bf + (size_t)node * 64);
    uint4 qd = rd[sub];
    const float bscale = inv_norm[node];
    const float betav = beta[0];
    float bd[8];
    bd[0] = bf_lo(qd.x) * bscale; bd[1] = bf_hi(qd.x) * bscale;
    bd[2] = bf_lo(qd.y) * bscale; bd[3] = bf_hi(qd.y) * bscale;
    bd[4] = bf_lo(qd.z) * bscale; bd[5] = bf_hi(qd.z) * bscale;
    bd[6] = bf_lo(qd.w) * bscale; bd[7] = bf_hi(qd.w) * bscale;

    float acc[8] = {0, 0, 0, 0, 0, 0, 0, 0};
    float denom = 0.0f;

    for (int base = kBeg; base < kEnd; base += 64) {
        const int chunk = min(64, kEnd - base);   // >= 1
        // one coalesced load of up to 64 src ids; clamp tail to a valid edge
        const int myid = sorted_src[base + min(lane, chunk - 1)];

        // first group's row (clamped; invalid slots gated by `valid` below)
        int s_cur = __shfl(myid, min(grp, chunk - 1), 64);
        uint4 q = reinterpret_cast<const uint4*>(feat_bf + (size_t)s_cur * 64)[sub];
        float in_cur = inv_norm[s_cur];

        for (int k0 = 0; k0 < chunk; k0 += 4) {
            // prefetch next group's row + inv_norm (overlaps compute below)
            uint4 qn = make_uint4(0u, 0u, 0u, 0u);
            float in_next = 0.0f;
            if (k0 + 4 < chunk) {                 // wave-uniform branch
                const int s_next = __shfl(myid, min(k0 + 4 + grp, chunk - 1), 64);
                qn = reinterpret_cast<const uint4*>(feat_bf + (size_t)s_next * 64)[sub];
                in_next = inv_norm[s_next];
            }

            float a[8];
            a[0] = bf_lo(q.x); a[1] = bf_hi(q.x);
            a[2] = bf_lo(q.y); a[3] = bf_hi(q.y);
            a[4] = bf_lo(q.z); a[5] = bf_hi(q.z);
            a[6] = bf_lo(q.w); a[7] = bf_hi(q.w);
            float dot = 0.0f;
            #pragma unroll
            for (int j = 0; j < 8; ++j) dot += a[j] * bd[j];
            #pragma unroll
            for (int off = 8; off > 0; off >>= 1)
                dot += __shfl_xor(dot, off, 64);
            const bool valid = (k0 + grp) < chunk;
            const float ee = valid ? __expf(betav * dot * in_cur) : 0.0f;
            #pragma unroll
            for (int j = 0; j < 8; ++j) acc[j] += ee * a[j];
            denom += ee;

            q = qn;
            in_cur = in_next;
        }
    }

    #pragma unroll
    for (int j = 0; j < 8; ++j) {
        acc[j] += __shfl_xor(acc[j], 16, 64);
        acc[j] += __shfl_xor(acc[j], 32, 64);
    }
    denom += __shfl_xor(denom, 16, 64);
    denom += __shfl_xor(denom, 32, 64);

    if (grp == 0) {
        const float scale = (kEnd > kBeg) ? (1.0f / denom) : 0.0f;
        float4* orow = reinterpret_cast<float4*>(out + (size_t)node * D_FEAT);
        orow[2 * sub] = make_float4(acc[0] * scale, acc[1] * scale,
                                    acc[2] * scale, acc[3] * scale);
        orow[2 * sub + 1] = make_float4(acc[4] * scale, acc[5] * scale,
                                        acc[6] * scale, acc[7] * scale);
    }
}

extern "C" void kernel_launch(void* const* d_in, const int* in_sizes, int n_in,
                              void* d_out, int out_size, void* d_ws, size_t ws_size,
                              hipStream_t stream) {
    const float* feat = (const float*)d_in[0];
    const float* beta = (const float*)d_in[1];
    const int*   src  = (const int*)d_in[2];
    const int*   dst  = (const int*)d_in[3];
    float* out = (float*)d_out;

    // ws layout: inv_norm[N] f32 | counts[N] i32 | offsets[N+1] i32 |
    //            rank[E] i32 | sorted_src[E] i32 | feat_bf[N*64] u32
    float*        inv_norm   = (float*)d_ws;
    int*          counts     = (int*)(inv_norm + N_NODES);
    int*          offsets    = counts + N_NODES;
    int*          rank       = offsets + (N_NODES + 1);
    int*          sorted_src = rank + N_EDGES;
    unsigned int* feat_bf    = (unsigned int*)(sorted_src + N_EDGES);

    hipMemsetAsync(counts, 0, (size_t)N_NODES * sizeof(int), stream);

    const int WPB = 4;              // waves per block
    const int BLOCK = WPB * 64;     // 256 threads

    {
        int blocks = (N_NODES + WPB - 1) / WPB;   // 12500 blocks -> 3.2M threads
        norm_kernel<<<blocks, BLOCK, 0, stream>>>(feat, inv_norm, feat_bf,
                                                  dst, counts, rank);
    }
    scan_kernel<<<S1_NBLK, S1_BLOCK, 0, stream>>>(counts, offsets);
    {
        int blocks = (N_EDGES + 255) / 256;       // one thread per edge
        scatter_kernel<<<blocks, 256, 0, stream>>>(src, dst, offsets, rank,
                                                   sorted_src);
    }
    {
        int blocks = (N_NODES + WPB - 1) / WPB;
        fused_agg<<<blocks, BLOCK, 0, stream>>>(feat_bf, inv_norm, offsets,
                                                sorted_src, beta, out);
    }
}

// Round 8
// 113.880 us; speedup vs baseline: 1.1813x; 1.1813x over previous
//
#include <hip/hip_runtime.h>

#define N_NODES 50000
#define N_EDGES 800000
#define D_FEAT  128
#define EPS     1e-12f

#define S1_BLOCK 256
#define S1_TILE  1024                                   // 4 elems/thread
#define S1_NBLK  ((N_NODES + S1_TILE - 1) / S1_TILE)    // 49

__device__ __forceinline__ unsigned int f2bf(float x) {
    unsigned int u = __float_as_uint(x);
    return (u + 0x7FFFu + ((u >> 16) & 1u)) >> 16;      // RNE
}
__device__ __forceinline__ float bf_lo(unsigned int w) {
    return __uint_as_float(w << 16);
}
__device__ __forceinline__ float bf_hi(unsigned int w) {
    return __uint_as_float(w & 0xFFFF0000u);
}

// ---------------------------------------------------------------------------
// K1: pure per-node inv_norm + packed bf16 copy. Half-wave (32 lanes) per
// node, float4 loads (16 B/lane), uint2 stores (8 B/lane). 8 nodes/block.
// 50000 % 8 == 0 -> no tail check.
// ---------------------------------------------------------------------------
__global__ void norm_kernel(const float* __restrict__ feat,
                            float* __restrict__ inv_norm,
                            unsigned int* __restrict__ feat_bf) {  // 64 words/row
    const int g   = threadIdx.x >> 5;            // 0..7 group in block
    const int sub = threadIdx.x & 31;            // lane in group
    const int node = blockIdx.x * 8 + g;
    const float4* row = reinterpret_cast<const float4*>(feat + (size_t)node * D_FEAT);
    float4 v = row[sub];
    unsigned int w0 = (f2bf(v.y) << 16) | f2bf(v.x);
    unsigned int w1 = (f2bf(v.w) << 16) | f2bf(v.z);
    *reinterpret_cast<uint2*>(feat_bf + (size_t)node * 64 + sub * 2) =
        make_uint2(w0, w1);
    float s = v.x * v.x + v.y * v.y + v.z * v.z + v.w * v.w;
    #pragma unroll
    for (int off = 16; off > 0; off >>= 1)       // stays within 32-lane group
        s += __shfl_xor(s, off, 64);
    if (sub == 0) {
        inv_norm[node] = 1.0f / fmaxf(sqrtf(s), EPS);
    }
}

// ---------------------------------------------------------------------------
// K2: per-edge dst count + within-node rank (atomic return). 1 thread/edge.
// ---------------------------------------------------------------------------
__global__ void count_rank_kernel(const int* __restrict__ dst,
                                  int* __restrict__ counts,
                                  int* __restrict__ rank) {
    const int e = blockIdx.x * blockDim.x + threadIdx.x;
    if (e >= N_EDGES) return;
    rank[e] = atomicAdd(&counts[dst[e]], 1);
}

// ---------------------------------------------------------------------------
// Scan phase 1: per-block scan of a 1024-elem tile (4/thread, int4).
// ---------------------------------------------------------------------------
__global__ void scan1_kernel(const int* __restrict__ counts,
                             int* __restrict__ offsets,
                             int* __restrict__ block_sums) {
    __shared__ int lds[S1_BLOCK];
    const int b = blockIdx.x, t = threadIdx.x;
    const int base = b * S1_TILE + t * 4;
    int v0 = 0, v1 = 0, v2 = 0, v3 = 0;
    if (base + 3 < N_NODES) {
        int4 v = *reinterpret_cast<const int4*>(counts + base);
        v0 = v.x; v1 = v.y; v2 = v.z; v3 = v.w;
    }
    const int tsum = v0 + v1 + v2 + v3;
    lds[t] = tsum;
    __syncthreads();
    for (int off = 1; off < S1_BLOCK; off <<= 1) {
        int x = (t >= off) ? lds[t - off] : 0;
        __syncthreads();
        lds[t] += x;
        __syncthreads();
    }
    const int excl = lds[t] - tsum;
    if (t == S1_BLOCK - 1) block_sums[b] = lds[t];
    if (base + 3 < N_NODES) {
        *reinterpret_cast<int4*>(offsets + base) =
            make_int4(excl, excl + v0, excl + v0 + v1, excl + v0 + v1 + v2);
    }
}

// ---------------------------------------------------------------------------
// Scan phase 2+3 fused: every block wave-scans the 49 block sums, adds its
// own block offset, writes offsets. Block 0 writes the grand total.
// ---------------------------------------------------------------------------
__global__ void scan23_kernel(const int* __restrict__ block_sums,
                              int* __restrict__ offsets) {
    __shared__ int sh[2];
    const int b = blockIdx.x, t = threadIdx.x;
    if (t < 64) {
        int v = (t < S1_NBLK) ? block_sums[t] : 0;
        int incl = v;
        #pragma unroll
        for (int off = 1; off < 64; off <<= 1) {
            int n = __shfl_up(incl, off, 64);
            if (t >= off) incl += n;
        }
        if (t == b) sh[0] = incl - v;
        if (t == S1_NBLK - 1) sh[1] = incl;
    }
    __syncthreads();
    const int base = b * S1_TILE + t * 4;
    if (base + 3 < N_NODES) {
        const int boff = sh[0];
        int4 v = *reinterpret_cast<const int4*>(offsets + base);
        v.x += boff; v.y += boff; v.z += boff; v.w += boff;
        *reinterpret_cast<int4*>(offsets + base) = v;
    }
    if (b == 0 && t == 0) offsets[N_NODES] = sh[1];
}

// ---------------------------------------------------------------------------
// K5: atomic-free scatter: sorted_src[offsets[dst[e]] + rank[e]] = src[e].
// ---------------------------------------------------------------------------
__global__ void scatter_kernel(const int* __restrict__ src,
                               const int* __restrict__ dst,
                               const int* __restrict__ offsets,
                               const int* __restrict__ rank,
                               int* __restrict__ sorted_src) {
    const int e = blockIdx.x * blockDim.x + threadIdx.x;
    if (e >= N_EDGES) return;
    sorted_src[offsets[dst[e]] + rank[e]] = src[e];
}

// ---------------------------------------------------------------------------
// K6: fused per-node weight + aggregation over bf16 rows.
// One wave per node; 4 edges/iter via 16-lane groups; software-pipelined.
// ---------------------------------------------------------------------------
__global__ void fused_agg(const unsigned int* __restrict__ feat_bf,
                          const float* __restrict__ inv_norm,
                          const int* __restrict__ offsets,
                          const int* __restrict__ sorted_src,
                          const float* __restrict__ beta,
                          float* __restrict__ out) {
    const int lane = threadIdx.x & 63;
    const int grp  = lane >> 4;       // 0..3  : edge slot
    const int sub  = lane & 15;       // lane within group
    const int node = blockIdx.x * (blockDim.x >> 6) + (threadIdx.x >> 6);
    if (node >= N_NODES) return;

    const int kBeg = offsets[node];
    const int kEnd = offsets[node + 1];

    const uint4* rd = reinterpret_cast<const uint4*>(feat_bf + (size_t)node * 64);
    uint4 qd = rd[sub];
    const float bscale = inv_norm[node];
    const float betav = beta[0];
    float bd[8];
    bd[0] = bf_lo(qd.x) * bscale; bd[1] = bf_hi(qd.x) * bscale;
    bd[2] = bf_lo(qd.y) * bscale; bd[3] = bf_hi(qd.y) * bscale;
    bd[4] = bf_lo(qd.z) * bscale; bd[5] = bf_hi(qd.z) * bscale;
    bd[6] = bf_lo(qd.w) * bscale; bd[7] = bf_hi(qd.w) * bscale;

    float acc[8] = {0, 0, 0, 0, 0, 0, 0, 0};
    float denom = 0.0f;

    for (int base = kBeg; base < kEnd; base += 64) {
        const int chunk = min(64, kEnd - base);   // >= 1
        const int myid = sorted_src[base + min(lane, chunk - 1)];

        int s_cur = __shfl(myid, min(grp, chunk - 1), 64);
        uint4 q = reinterpret_cast<const uint4*>(feat_bf + (size_t)s_cur * 64)[sub];
        float in_cur = inv_norm[s_cur];

        for (int k0 = 0; k0 < chunk; k0 += 4) {
            uint4 qn = make_uint4(0u, 0u, 0u, 0u);
            float in_next = 0.0f;
            if (k0 + 4 < chunk) {                 // wave-uniform branch
                const int s_next = __shfl(myid, min(k0 + 4 + grp, chunk - 1), 64);
                qn = reinterpret_cast<const uint4*>(feat_bf + (size_t)s_next * 64)[sub];
                in_next = inv_norm[s_next];
            }

            float a[8];
            a[0] = bf_lo(q.x); a[1] = bf_hi(q.x);
            a[2] = bf_lo(q.y); a[3] = bf_hi(q.y);
            a[4] = bf_lo(q.z); a[5] = bf_hi(q.z);
            a[6] = bf_lo(q.w); a[7] = bf_hi(q.w);
            float dot = 0.0f;
            #pragma unroll
            for (int j = 0; j < 8; ++j) dot += a[j] * bd[j];
            #pragma unroll
            for (int off = 8; off > 0; off >>= 1)
                dot += __shfl_xor(dot, off, 64);
            const bool valid = (k0 + grp) < chunk;
            const float ee = valid ? __expf(betav * dot * in_cur) : 0.0f;
            #pragma unroll
            for (int j = 0; j < 8; ++j) acc[j] += ee * a[j];
            denom += ee;

            q = qn;
            in_cur = in_next;
        }
    }

    #pragma unroll
    for (int j = 0; j < 8; ++j) {
        acc[j] += __shfl_xor(acc[j], 16, 64);
        acc[j] += __shfl_xor(acc[j], 32, 64);
    }
    denom += __shfl_xor(denom, 16, 64);
    denom += __shfl_xor(denom, 32, 64);

    if (grp == 0) {
        const float scale = (kEnd > kBeg) ? (1.0f / denom) : 0.0f;
        float4* orow = reinterpret_cast<float4*>(out + (size_t)node * D_FEAT);
        orow[2 * sub] = make_float4(acc[0] * scale, acc[1] * scale,
                                    acc[2] * scale, acc[3] * scale);
        orow[2 * sub + 1] = make_float4(acc[4] * scale, acc[5] * scale,
                                        acc[6] * scale, acc[7] * scale);
    }
}

extern "C" void kernel_launch(void* const* d_in, const int* in_sizes, int n_in,
                              void* d_out, int out_size, void* d_ws, size_t ws_size,
                              hipStream_t stream) {
    const float* feat = (const float*)d_in[0];
    const float* beta = (const float*)d_in[1];
    const int*   src  = (const int*)d_in[2];
    const int*   dst  = (const int*)d_in[3];
    float* out = (float*)d_out;

    // ws layout: inv_norm[N] f32 | counts[N] i32 | offsets[N+1] i32 |
    //            block_sums[49] i32 | rank[E] i32 | sorted_src[E] i32 |
    //            feat_bf[N*64] u32
    float*        inv_norm   = (float*)d_ws;
    int*          counts     = (int*)(inv_norm + N_NODES);
    int*          offsets    = counts + N_NODES;
    int*          block_sums = offsets + (N_NODES + 1);
    int*          rank       = block_sums + S1_NBLK;
    int*          sorted_src = rank + N_EDGES;
    unsigned int* feat_bf    = (unsigned int*)(sorted_src + N_EDGES);

    hipMemsetAsync(counts, 0, (size_t)N_NODES * sizeof(int), stream);

    norm_kernel<<<N_NODES / 8, 256, 0, stream>>>(feat, inv_norm, feat_bf);
    count_rank_kernel<<<(N_EDGES + 255) / 256, 256, 0, stream>>>(dst, counts, rank);
    scan1_kernel<<<S1_NBLK, S1_BLOCK, 0, stream>>>(counts, offsets, block_sums);
    scan23_kernel<<<S1_NBLK, S1_BLOCK, 0, stream>>>(block_sums, offsets);
    scatter_kernel<<<(N_EDGES + 255) / 256, 256, 0, stream>>>(src, dst, offsets,
                                                              rank, sorted_src);
    {
        const int WPB = 4;
        int blocks = (N_NODES + WPB - 1) / WPB;
        fused_agg<<<blocks, WPB * 64, 0, stream>>>(feat_bf, inv_norm, offsets,
                                                   sorted_src, beta, out);
    }
}

// Round 9
// 108.950 us; speedup vs baseline: 1.2348x; 1.0453x over previous
//
#include <hip/hip_runtime.h>

#define N_NODES 50000
#define N_EDGES 800000
#define D_FEAT  128
#define EPS     1e-12f

#define S1_BLOCK 256
#define S1_TILE  1024                                   // 4 elems/thread
#define S1_NBLK  ((N_NODES + S1_TILE - 1) / S1_TILE)    // 49

__device__ __forceinline__ unsigned int f2bf(float x) {
    unsigned int u = __float_as_uint(x);
    return (u + 0x7FFFu + ((u >> 16) & 1u)) >> 16;      // RNE
}
__device__ __forceinline__ float bf_lo(unsigned int w) {
    return __uint_as_float(w << 16);
}
__device__ __forceinline__ float bf_hi(unsigned int w) {
    return __uint_as_float(w & 0xFFFF0000u);
}

// ---------------------------------------------------------------------------
// K1: per-node inv_norm + packed bf16 copy; ALSO zeroes counts[] (replaces a
// 44 us fillBuffer dispatch). Half-wave (32 lanes) per node, float4 loads.
// ---------------------------------------------------------------------------
__global__ void norm_kernel(const float* __restrict__ feat,
                            float* __restrict__ inv_norm,
                            unsigned int* __restrict__ feat_bf,   // 64 words/row
                            int* __restrict__ counts) {
    const int tid = blockIdx.x * blockDim.x + threadIdx.x;
    if (tid < N_NODES) counts[tid] = 0;                  // fused zero-fill

    const int g   = threadIdx.x >> 5;            // 0..7 group in block
    const int sub = threadIdx.x & 31;            // lane in group
    const int node = blockIdx.x * 8 + g;
    const float4* row = reinterpret_cast<const float4*>(feat + (size_t)node * D_FEAT);
    float4 v = row[sub];
    unsigned int w0 = (f2bf(v.y) << 16) | f2bf(v.x);
    unsigned int w1 = (f2bf(v.w) << 16) | f2bf(v.z);
    *reinterpret_cast<uint2*>(feat_bf + (size_t)node * 64 + sub * 2) =
        make_uint2(w0, w1);
    float s = v.x * v.x + v.y * v.y + v.z * v.z + v.w * v.w;
    #pragma unroll
    for (int off = 16; off > 0; off >>= 1)       // stays within 32-lane group
        s += __shfl_xor(s, off, 64);
    if (sub == 0) {
        inv_norm[node] = 1.0f / fmaxf(sqrtf(s), EPS);
    }
}

// ---------------------------------------------------------------------------
// K2: per-edge dst count + within-node rank (atomic return). 1 thread/edge.
// ---------------------------------------------------------------------------
__global__ void count_rank_kernel(const int* __restrict__ dst,
                                  int* __restrict__ counts,
                                  int* __restrict__ rank) {
    const int e = blockIdx.x * blockDim.x + threadIdx.x;
    if (e >= N_EDGES) return;
    rank[e] = atomicAdd(&counts[dst[e]], 1);
}

// ---------------------------------------------------------------------------
// Scan phase 1: per-block scan of a 1024-elem tile (4/thread, int4).
// ---------------------------------------------------------------------------
__global__ void scan1_kernel(const int* __restrict__ counts,
                             int* __restrict__ offsets,
                             int* __restrict__ block_sums) {
    __shared__ int lds[S1_BLOCK];
    const int b = blockIdx.x, t = threadIdx.x;
    const int base = b * S1_TILE + t * 4;
    int v0 = 0, v1 = 0, v2 = 0, v3 = 0;
    if (base + 3 < N_NODES) {
        int4 v = *reinterpret_cast<const int4*>(counts + base);
        v0 = v.x; v1 = v.y; v2 = v.z; v3 = v.w;
    }
    const int tsum = v0 + v1 + v2 + v3;
    lds[t] = tsum;
    __syncthreads();
    for (int off = 1; off < S1_BLOCK; off <<= 1) {
        int x = (t >= off) ? lds[t - off] : 0;
        __syncthreads();
        lds[t] += x;
        __syncthreads();
    }
    const int excl = lds[t] - tsum;
    if (t == S1_BLOCK - 1) block_sums[b] = lds[t];
    if (base + 3 < N_NODES) {
        *reinterpret_cast<int4*>(offsets + base) =
            make_int4(excl, excl + v0, excl + v0 + v1, excl + v0 + v1 + v2);
    }
}

// ---------------------------------------------------------------------------
// Scan phase 2+3 fused: every block wave-scans the 49 block sums, adds its
// own block offset, writes offsets. Block 0 writes the grand total.
// ---------------------------------------------------------------------------
__global__ void scan23_kernel(const int* __restrict__ block_sums,
                              int* __restrict__ offsets) {
    __shared__ int sh[2];
    const int b = blockIdx.x, t = threadIdx.x;
    if (t < 64) {
        int v = (t < S1_NBLK) ? block_sums[t] : 0;
        int incl = v;
        #pragma unroll
        for (int off = 1; off < 64; off <<= 1) {
            int n = __shfl_up(incl, off, 64);
            if (t >= off) incl += n;
        }
        if (t == b) sh[0] = incl - v;
        if (t == S1_NBLK - 1) sh[1] = incl;
    }
    __syncthreads();
    const int base = b * S1_TILE + t * 4;
    if (base + 3 < N_NODES) {
        const int boff = sh[0];
        int4 v = *reinterpret_cast<const int4*>(offsets + base);
        v.x += boff; v.y += boff; v.z += boff; v.w += boff;
        *reinterpret_cast<int4*>(offsets + base) = v;
    }
    if (b == 0 && t == 0) offsets[N_NODES] = sh[1];
}

// ---------------------------------------------------------------------------
// K5: atomic-free scatter: sorted_src[offsets[dst[e]] + rank[e]] = src[e].
// ---------------------------------------------------------------------------
__global__ void scatter_kernel(const int* __restrict__ src,
                               const int* __restrict__ dst,
                               const int* __restrict__ offsets,
                               const int* __restrict__ rank,
                               int* __restrict__ sorted_src) {
    const int e = blockIdx.x * blockDim.x + threadIdx.x;
    if (e >= N_EDGES) return;
    sorted_src[offsets[dst[e]] + rank[e]] = src[e];
}

// ---------------------------------------------------------------------------
// K6: fused per-node weight + aggregation over bf16 rows.
// One wave per node; 4 edges/iter via 16-lane groups; software-pipelined.
// ---------------------------------------------------------------------------
__global__ void fused_agg(const unsigned int* __restrict__ feat_bf,
                          const float* __restrict__ inv_norm,
                          const int* __restrict__ offsets,
                          const int* __restrict__ sorted_src,
                          const float* __restrict__ beta,
                          float* __restrict__ out) {
    const int lane = threadIdx.x & 63;
    const int grp  = lane >> 4;       // 0..3  : edge slot
    const int sub  = lane & 15;       // lane within group
    const int node = blockIdx.x * (blockDim.x >> 6) + (threadIdx.x >> 6);
    if (node >= N_NODES) return;

    const int kBeg = offsets[node];
    const int kEnd = offsets[node + 1];

    const uint4* rd = reinterpret_cast<const uint4*>(feat_bf + (size_t)node * 64);
    uint4 qd = rd[sub];
    const float bscale = inv_norm[node];
    const float betav = beta[0];
    float bd[8];
    bd[0] = bf_lo(qd.x) * bscale; bd[1] = bf_hi(qd.x) * bscale;
    bd[2] = bf_lo(qd.y) * bscale; bd[3] = bf_hi(qd.y) * bscale;
    bd[4] = bf_lo(qd.z) * bscale; bd[5] = bf_hi(qd.z) * bscale;
    bd[6] = bf_lo(qd.w) * bscale; bd[7] = bf_hi(qd.w) * bscale;

    float acc[8] = {0, 0, 0, 0, 0, 0, 0, 0};
    float denom = 0.0f;

    for (int base = kBeg; base < kEnd; base += 64) {
        const int chunk = min(64, kEnd - base);   // >= 1
        const int myid = sorted_src[base + min(lane, chunk - 1)];

        int s_cur = __shfl(myid, min(grp, chunk - 1), 64);
        uint4 q = reinterpret_cast<const uint4*>(feat_bf + (size_t)s_cur * 64)[sub];
        float in_cur = inv_norm[s_cur];

        for (int k0 = 0; k0 < chunk; k0 += 4) {
            uint4 qn = make_uint4(0u, 0u, 0u, 0u);
            float in_next = 0.0f;
            if (k0 + 4 < chunk) {                 // wave-uniform branch
                const int s_next = __shfl(myid, min(k0 + 4 + grp, chunk - 1), 64);
                qn = reinterpret_cast<const uint4*>(feat_bf + (size_t)s_next * 64)[sub];
                in_next = inv_norm[s_next];
            }

            float a[8];
            a[0] = bf_lo(q.x); a[1] = bf_hi(q.x);
            a[2] = bf_lo(q.y); a[3] = bf_hi(q.y);
            a[4] = bf_lo(q.z); a[5] = bf_hi(q.z);
            a[6] = bf_lo(q.w); a[7] = bf_hi(q.w);
            float dot = 0.0f;
            #pragma unroll
            for (int j = 0; j < 8; ++j) dot += a[j] * bd[j];
            #pragma unroll
            for (int off = 8; off > 0; off >>= 1)
                dot += __shfl_xor(dot, off, 64);
            const bool valid = (k0 + grp) < chunk;
            const float ee = valid ? __expf(betav * dot * in_cur) : 0.0f;
            #pragma unroll
            for (int j = 0; j < 8; ++j) acc[j] += ee * a[j];
            denom += ee;

            q = qn;
            in_cur = in_next;
        }
    }

    #pragma unroll
    for (int j = 0; j < 8; ++j) {
        acc[j] += __shfl_xor(acc[j], 16, 64);
        acc[j] += __shfl_xor(acc[j], 32, 64);
    }
    denom += __shfl_xor(denom, 16, 64);
    denom += __shfl_xor(denom, 32, 64);

    if (grp == 0) {
        const float scale = (kEnd > kBeg) ? (1.0f / denom) : 0.0f;
        float4* orow = reinterpret_cast<float4*>(out + (size_t)node * D_FEAT);
        orow[2 * sub] = make_float4(acc[0] * scale, acc[1] * scale,
                                    acc[2] * scale, acc[3] * scale);
        orow[2 * sub + 1] = make_float4(acc[4] * scale, acc[5] * scale,
                                        acc[6] * scale, acc[7] * scale);
    }
}

extern "C" void kernel_launch(void* const* d_in, const int* in_sizes, int n_in,
                              void* d_out, int out_size, void* d_ws, size_t ws_size,
                              hipStream_t stream) {
    const float* feat = (const float*)d_in[0];
    const float* beta = (const float*)d_in[1];
    const int*   src  = (const int*)d_in[2];
    const int*   dst  = (const int*)d_in[3];
    float* out = (float*)d_out;

    // ws layout: inv_norm[N] f32 | counts[N] i32 | offsets[N+1] i32 |
    //            block_sums[49] i32 | rank[E] i32 | sorted_src[E] i32 |
    //            feat_bf[N*64] u32
    float*        inv_norm   = (float*)d_ws;
    int*          counts     = (int*)(inv_norm + N_NODES);
    int*          offsets    = counts + N_NODES;
    int*          block_sums = offsets + (N_NODES + 1);
    int*          rank       = block_sums + S1_NBLK;
    int*          sorted_src = rank + N_EDGES;
    unsigned int* feat_bf    = (unsigned int*)(sorted_src + N_EDGES);

    norm_kernel<<<N_NODES / 8, 256, 0, stream>>>(feat, inv_norm, feat_bf, counts);
    count_rank_kernel<<<(N_EDGES + 255) / 256, 256, 0, stream>>>(dst, counts, rank);
    scan1_kernel<<<S1_NBLK, S1_BLOCK, 0, stream>>>(counts, offsets, block_sums);
    scan23_kernel<<<S1_NBLK, S1_BLOCK, 0, stream>>>(block_sums, offsets);
    scatter_kernel<<<(N_EDGES + 255) / 256, 256, 0, stream>>>(src, dst, offsets,
                                                              rank, sorted_src);
    {
        const int WPB = 4;
        int blocks = (N_NODES + WPB - 1) / WPB;
        fused_agg<<<blocks, WPB * 64, 0, stream>>>(feat_bf, inv_norm, offsets,
                                                   sorted_src, beta, out);
    }
}